// Round 13
// baseline (275.769 us; speedup 1.0000x reference)
//
#include <hip/hip_runtime.h>

#define NPG    50
#define HF     128
#define FDIM   64
#define NGRAPH 2048
#define NNODES 102400
#define EPG    400
#define SP     72     // featT row stride (bf16)
#define CSI    36     // cnt row stride (ints), 2 counts/int, 16B-aligned rows
#define HB     136    // hbuf row stride (bf16), 16B-aligned rows

typedef __attribute__((ext_vector_type(8))) short bf16x8;
typedef __attribute__((ext_vector_type(4))) float floatx4;

__device__ __forceinline__ float leaky(float x, float s) { return x >= 0.f ? x : x * s; }
__device__ __forceinline__ unsigned short f2bf(float f) {   // RNE fp32->bf16
    unsigned u = __float_as_uint(f);
    return (unsigned short)((u + 0x7fffu + ((u >> 16) & 1u)) >> 16);
}
__device__ __forceinline__ float bf2f(unsigned short h) {
    return __uint_as_float(((unsigned)h) << 16);
}
__device__ __forceinline__ int fkey(float f) { int b = __float_as_int(f); return b >= 0 ? b : b ^ 0x7fffffff; }
__device__ __forceinline__ float funkey(int k) { return __int_as_float(k >= 0 ? k : k ^ 0x7fffffff); }

// Build transposed bf16 weights: wt0[256][64] = [W0|resW0]^T, wt1/wt2[128][128] = W^T
__global__ void prep_w(const float* __restrict__ W0, const float* __restrict__ rW0,
                       const float* __restrict__ W1, const float* __restrict__ W2,
                       unsigned short* __restrict__ wt0, unsigned short* __restrict__ wt1,
                       unsigned short* __restrict__ wt2) {
    int i = blockIdx.x * 256 + threadIdx.x;
    if (i < 256 * 64) {
        int n = i >> 6, k = i & 63;
        float v = (n < 128) ? W0[k * 128 + n] : rW0[k * 128 + (n - 128)];
        wt0[i] = f2bf(v);
    }
    if (i < 128 * 128) {
        int n = i >> 7, k = i & 127;
        wt1[i] = f2bf(W1[k * 128 + n]);
        wt2[i] = f2bf(W2[k * 128 + n]);
    }
}

// One GAT layer, fully in-block.  hbuf: on entry RESW holds nothing (res is
// produced here); on exit holds this layer's y (next layer's A-frag source).
// prevY: 8 uints of packed bf16 y this thread produced LAST layer -- exactly
// the (row,col) fragment this thread needs as residual this layer (!RESW).
// No float atomics; all cross-wave float reductions via owned slots.
template <int K, bool RESW>
__device__ __forceinline__ void gat_layer(
    const bf16x8* afr_in,                       // RESW: preloaded A-frags
    const unsigned short* __restrict__ Wt,
    const float* __restrict__ al, const float* __restrict__ ar,
    const float* __restrict__ gbl,              // this layer's [g(128)|b(128)] in LDS
    float* __restrict__ out, int layer, int g, int t,
    unsigned* prevY,
    unsigned short* featT, unsigned short* hbuf, int* cnt,
    float* el_s, float* er_s, float* rden_s, int* elmax_i,
    float* lnp, float* lnq, float* psum4)
{
    const int w = t >> 6, lane = t & 63, quad = lane >> 4, l16 = lane & 15;
    constexpr int KS = K / 32;
    const int mt = w & 3;
    int mrow = mt * 16 + l16;
    if (mrow >= NPG) mrow = NPG - 1;
    const floatx4 zf = {0.f, 0.f, 0.f, 0.f};

    // ---- A-fragments ----
    bf16x8 afr[KS];
    if constexpr (RESW) {
#pragma unroll
        for (int ks = 0; ks < KS; ++ks) afr[ks] = afr_in[ks];
    } else {
#pragma unroll
        for (int ks = 0; ks < KS; ++ks)
            afr[ks] = *(const bf16x8*)&hbuf[mrow * HB + ks * 32 + quad * 8];
    }

    // ---- GEMM via MFMA + el/er + featT/res stores ----
    if constexpr (RESW) {
        // two passes of 4 N-tiles: halves peak accumulator regs (32->16).
        // w<4: half h covers cols of head h exactly.  w>=4: res cols -> hbuf.
#pragma unroll
        for (int half = 0; half < 2; ++half) {
            const int nb = (w >> 2) * 8 + half * 4;
            floatx4 acc[4];
#pragma unroll
            for (int nt = 0; nt < 4; ++nt) acc[nt] = zf;
#pragma unroll
            for (int nt = 0; nt < 4; ++nt) {
                const unsigned short* wrow = Wt + (size_t)((nb + nt) * 16 + l16) * K;
#pragma unroll
                for (int ks = 0; ks < KS; ++ks) {
                    bf16x8 b = *(const bf16x8*)(wrow + ks * 32 + quad * 8);
                    acc[nt] = __builtin_amdgcn_mfma_f32_16x16x32_bf16(afr[ks], b, acc[nt], 0, 0, 0);
                }
            }
            if (w < 4) {
                float pe[4] = {0,0,0,0}, pr[4] = {0,0,0,0};
#pragma unroll
                for (int nt = 0; nt < 4; ++nt) {
                    int col = (half * 4 + nt) * 16 + l16;
                    float av = al[col], rv = ar[col];
#pragma unroll
                    for (int r = 0; r < 4; ++r) {
                        pe[r] = fmaf(acc[nt][r], av, pe[r]);
                        pr[r] = fmaf(acc[nt][r], rv, pr[r]);
                    }
                }
#pragma unroll
                for (int m = 1; m <= 8; m <<= 1) {
#pragma unroll
                    for (int r = 0; r < 4; ++r) {
                        pe[r] += __shfl_xor(pe[r], m, 64);
                        pr[r] += __shfl_xor(pr[r], m, 64);
                    }
                }
                if (l16 == 0) {
#pragma unroll
                    for (int r = 0; r < 4; ++r) {
                        int row = mt * 16 + quad * 4 + r;
                        el_s[half * 64 + row] = pe[r];
                        er_s[half * 64 + row] = pr[r];
                        atomicMax(&elmax_i[half], fkey(pe[r]));  // int max: exact
                    }
                }
            }
#pragma unroll
            for (int nt = 0; nt < 4; ++nt) {
                int n = (nb + nt) * 16 + l16;
                if (n < HF) {
                    unsigned lo = (unsigned)f2bf(acc[nt][0]) | ((unsigned)f2bf(acc[nt][1]) << 16);
                    unsigned hi = (unsigned)f2bf(acc[nt][2]) | ((unsigned)f2bf(acc[nt][3]) << 16);
                    uint2 pk = {lo, hi};
                    *(uint2*)&featT[n * SP + mt * 16 + quad * 4] = pk;
                } else {
#pragma unroll
                    for (int r = 0; r < 4; ++r) {
                        int d = mt * 16 + quad * 4 + r;
                        if (d < NPG) hbuf[d * HB + (n - HF)] = f2bf(acc[nt][r]);
                    }
                }
            }
        }
    } else {
        const int ntbase = (w >> 2) * 4;
        floatx4 acc[4];
#pragma unroll
        for (int nt = 0; nt < 4; ++nt) acc[nt] = zf;
#pragma unroll
        for (int nt = 0; nt < 4; ++nt) {
            const unsigned short* wrow = Wt + (size_t)((ntbase + nt) * 16 + l16) * K;
#pragma unroll
            for (int ks = 0; ks < KS; ++ks) {
                bf16x8 b = *(const bf16x8*)(wrow + ks * 32 + quad * 8);
                acc[nt] = __builtin_amdgcn_mfma_f32_16x16x32_bf16(afr[ks], b, acc[nt], 0, 0, 0);
            }
        }
        {
            float pe[4] = {0,0,0,0}, pr[4] = {0,0,0,0};
#pragma unroll
            for (int nt = 0; nt < 4; ++nt) {
                int col = (ntbase + nt) * 16 + l16;
                float av = al[col], rv = ar[col];
#pragma unroll
                for (int r = 0; r < 4; ++r) {
                    pe[r] = fmaf(acc[nt][r], av, pe[r]);
                    pr[r] = fmaf(acc[nt][r], rv, pr[r]);
                }
            }
#pragma unroll
            for (int m = 1; m <= 8; m <<= 1) {
#pragma unroll
                for (int r = 0; r < 4; ++r) {
                    pe[r] += __shfl_xor(pe[r], m, 64);
                    pr[r] += __shfl_xor(pr[r], m, 64);
                }
            }
            if (l16 == 0) {
                int hd = w >> 2;
#pragma unroll
                for (int r = 0; r < 4; ++r) {
                    int row = mt * 16 + quad * 4 + r;
                    el_s[hd * 64 + row] = pe[r];
                    er_s[hd * 64 + row] = pr[r];
                    atomicMax(&elmax_i[hd], fkey(pe[r]));
                }
            }
        }
#pragma unroll
        for (int nt = 0; nt < 4; ++nt) {
            int n = (ntbase + nt) * 16 + l16;
            unsigned lo = (unsigned)f2bf(acc[nt][0]) | ((unsigned)f2bf(acc[nt][1]) << 16);
            unsigned hi = (unsigned)f2bf(acc[nt][2]) | ((unsigned)f2bf(acc[nt][3]) << 16);
            uint2 pk = {lo, hi};
            *(uint2*)&featT[n * SP + mt * 16 + quad * 4] = pk;
        }
    }
    __syncthreads();   // B1

    // ---- exp A-frag + aggregation MFMA + epilogue ----
    const int hd = w >> 2, amt = w & 3;
    const int d = amt * 16 + l16;    // A-frag dst row (>=NPG rows: cnt is zero)

    // max_s leaky(el+er) = leaky(max_s el + er)  (leaky monotone)
    const float erd = er_s[hd * 64 + d];
    const float md = leaky(funkey(elmax_i[hd]) + erd, 0.2f);
    float elv[16];
    *(float4*)&elv[0]  = *(const float4*)&el_s[hd * 64 + quad * 8];
    *(float4*)&elv[4]  = *(const float4*)&el_s[hd * 64 + quad * 8 + 4];
    *(float4*)&elv[8]  = *(const float4*)&el_s[hd * 64 + 32 + quad * 8];
    *(float4*)&elv[12] = *(const float4*)&el_s[hd * 64 + 32 + quad * 8 + 4];
    int4 ci0 = *(const int4*)&cnt[d * CSI + quad * 4];
    int4 ci1 = *(const int4*)&cnt[d * CSI + 16 + quad * 4];

    bf16x8 ap[2];
    float rowsum = 0.f;
#pragma unroll
    for (int ks = 0; ks < 2; ++ks) {
        const int* ci = ks ? (const int*)&ci1 : (const int*)&ci0;
        bf16x8 a;
#pragma unroll
        for (int j = 0; j < 8; ++j) {
            float e = elv[ks * 8 + j] + erd;
            e = fmaxf(e, 0.2f * e);                 // leaky (slope < 1)
            float p = __expf(e - md);
            int c = (ci[j >> 1] >> ((j & 1) * 16)) & 0xffff;
            unsigned short xb = f2bf((float)c * p); // c==0 -> exact 0
            a[j] = (short)xb;
            rowsum += bf2f(xb);
        }
        ap[ks] = a;
    }
    rowsum += __shfl_xor(rowsum, 16, 64);
    rowsum += __shfl_xor(rowsum, 32, 64);
    if (quad == 0) rden_s[hd * 64 + d] = 1.f / fmaxf(rowsum, 1e-30f);

    floatx4 ag[4];
#pragma unroll
    for (int nt = 0; nt < 4; ++nt) ag[nt] = zf;
#pragma unroll
    for (int nt = 0; nt < 4; ++nt) {
        const unsigned short* fr = &featT[(hd * 64 + nt * 16 + l16) * SP];
#pragma unroll
        for (int ks = 0; ks < 2; ++ks) {
            bf16x8 b = *(const bf16x8*)(fr + ks * 32 + quad * 8);
            ag[nt] = __builtin_amdgcn_mfma_f32_16x16x32_bf16(ap[ks], b, ag[nt], 0, 0, 0);
        }
    }

    // scale + residual; LN partials into uniquely-owned slots (deterministic).
    // Residual: RESW from hbuf (res cols); else from prevY registers (bitwise
    // identical to the hbuf bf16 values -- same thread wrote them last layer).
    float s1[4] = {0,0,0,0}, s2[4] = {0,0,0,0};
#pragma unroll
    for (int r = 0; r < 4; ++r) {
        int dd = amt * 16 + quad * 4 + r;
        float rdv = rden_s[hd * 64 + (dd < 64 ? dd : 63)];
        int dc = dd < NPG ? dd : NPG - 1;
#pragma unroll
        for (int nt = 0; nt < 4; ++nt) {
            float rv;
            if constexpr (RESW) {
                rv = bf2f(hbuf[dc * HB + hd * 64 + nt * 16 + l16]);
            } else {
                unsigned pk = prevY[nt * 2 + (r >> 1)];
                rv = bf2f((unsigned short)((r & 1) ? (pk >> 16) : (pk & 0xffffu)));
            }
            float vv = fmaf(ag[nt][r], rdv, rv);
            ag[nt][r] = vv;
            s1[r] += vv;
            s2[r] = fmaf(vv, vv, s2[r]);
        }
    }
#pragma unroll
    for (int m = 1; m <= 8; m <<= 1) {
#pragma unroll
        for (int r = 0; r < 4; ++r) {
            s1[r] += __shfl_xor(s1[r], m, 64);
            s2[r] += __shfl_xor(s2[r], m, 64);
        }
    }
    if (l16 == 0) {
#pragma unroll
        for (int r = 0; r < 4; ++r) {
            int dd = amt * 16 + quad * 4 + r;   // slot [hd][dd]: single writer
            lnp[hd * 64 + dd] = s1[r];
            lnq[hd * 64 + dd] = s2[r];
        }
    }
    __syncthreads();   // B2: LN slots written; hbuf/featT reads done

    // re-arm elmax for the next layer (reads finished at B2, writes after B3)
    if (t < 2) elmax_i[t] = (int)0x80000000;

    // normalize + affine + leaky -> y into hbuf + prevY; readout from fp32 y
    float part[4] = {0, 0, 0, 0};
#pragma unroll
    for (int r = 0; r < 4; ++r) {
        int dd = amt * 16 + quad * 4 + r;
        if (dd < NPG) {
            float mus = lnp[dd] + lnp[64 + dd];         // fixed order: head0 + head1
            float sqs = lnq[dd] + lnq[64 + dd];
            float mu = mus * (1.f / HF);
            float rs = rsqrtf(sqs * (1.f / HF) - mu * mu + 1e-5f);
#pragma unroll
            for (int nt = 0; nt < 4; ++nt) {
                int col = hd * 64 + nt * 16 + l16;
                float y = (ag[nt][r] - mu) * rs * gbl[col] + gbl[HF + col];
                y = leaky(y, 0.1f);
                unsigned short xb = f2bf(y);
                hbuf[dd * HB + col] = xb;
                unsigned idx = nt * 2 + (r >> 1);
                prevY[idx] = (r & 1) ? ((prevY[idx] & 0x0000ffffu) | ((unsigned)xb << 16))
                                     : ((prevY[idx] & 0xffff0000u) | (unsigned)xb);
                part[nt] += y;
            }
        }
    }
    // sum part over quads in-wave; slot [amt][col]: single writer per slot
#pragma unroll
    for (int nt = 0; nt < 4; ++nt) {
        part[nt] += __shfl_xor(part[nt], 16, 64);
        part[nt] += __shfl_xor(part[nt], 32, 64);
    }
    if (quad == 0) {
#pragma unroll
        for (int nt = 0; nt < 4; ++nt)
            psum4[amt * HF + hd * 64 + nt * 16 + l16] = part[nt];
    }
    __syncthreads();   // B3: y visible (next layer A-frags), psum4 complete

    if (t < FDIM) {
        float s = 0.f;
#pragma unroll
        for (int a4 = 0; a4 < 4; ++a4)                   // fixed summation order
            s += psum4[a4 * HF + t] + psum4[a4 * HF + t + FDIM];
        out[(size_t)g * (3 * FDIM) + layer * FDIM + t] = leaky(s * (1.f / (2 * NPG)), 0.1f);
    }
    // no re-zero needed: lnp/lnq/psum4 slots are fully overwritten next layer
}

// One block per graph runs all 3 layers (edges never cross graphs -> no grid
// sync; h carried in LDS + registers, never touches HBM).
// (512,6): 85-reg cap targets 6 waves/SIMD = 3 blocks/CU (R12's 88 -> 2
// blocks).  L0 GEMM two-pass keeps peak acc at 16 AGPRs to fit.
__global__ __launch_bounds__(512, 6) void gat3_kernel(
    const float* __restrict__ x,
    const unsigned short* __restrict__ wt0,
    const unsigned short* __restrict__ wt1,
    const unsigned short* __restrict__ wt2,
    const float* __restrict__ al0, const float* __restrict__ ar0,
    const float* __restrict__ al1, const float* __restrict__ ar1,
    const float* __restrict__ al2, const float* __restrict__ ar2,
    const float* __restrict__ g0, const float* __restrict__ b0,
    const float* __restrict__ g1, const float* __restrict__ b1,
    const float* __restrict__ g2, const float* __restrict__ b2,
    const int* __restrict__ src, const int* __restrict__ dst,
    float* __restrict__ out)
{
    __shared__ unsigned short featT[HF * SP];   // 18432 B
    __shared__ unsigned short hbuf[NPG * HB];   // 13600 B (res/h/y carrier)
    __shared__ int cnt[64 * CSI];               // 9216 B, rows 50..63 stay zero
    __shared__ float el_s[128], er_s[128], rden_s[128];
    __shared__ int elmax_i[2];
    __shared__ float lnp[128], lnq[128];        // LN partials [head][row]
    __shared__ float psum4[4 * HF];             // readout partials [amt][col]
    __shared__ float gb_s[3 * 2 * HF];          // 3 layers x [g|b]

    const int g = blockIdx.x, t = threadIdx.x;
    const int nbase = g * NPG;
    const int w = t >> 6, lane = t & 63, quad = lane >> 4, l16 = lane & 15;

    // independent global loads at cycle 0
    int es = 0, ed = 0;
    if (t < EPG) { es = src[g * EPG + t] - nbase; ed = dst[g * EPG + t] - nbase; }

    // L0 A-fragments from global fp32 x (early issue)
    const int mt = w & 3;
    int mrow = mt * 16 + l16;
    if (mrow >= NPG) mrow = NPG - 1;
    bf16x8 afr0[2];
    {
        const float* hrow = x + (size_t)(nbase + mrow) * 64;
#pragma unroll
        for (int ks = 0; ks < 2; ++ks) {
            int k0 = ks * 32 + quad * 8;
            float4 p0 = *(const float4*)(hrow + k0);
            float4 p1 = *(const float4*)(hrow + k0 + 4);
            bf16x8 a;
            a[0] = (short)f2bf(p0.x); a[1] = (short)f2bf(p0.y);
            a[2] = (short)f2bf(p0.z); a[3] = (short)f2bf(p0.w);
            a[4] = (short)f2bf(p1.x); a[5] = (short)f2bf(p1.y);
            a[6] = (short)f2bf(p1.z); a[7] = (short)f2bf(p1.w);
            afr0[ks] = a;
        }
    }

    // init
    for (int i = t; i < 64 * CSI; i += 512) cnt[i] = 0;
    if (t < 2) elmax_i[t] = (int)0x80000000;
    if (t < HF) {
        gb_s[t] = g0[t];       gb_s[HF + t] = b0[t];
        gb_s[256 + t] = g1[t]; gb_s[256 + HF + t] = b1[t];
        gb_s[512 + t] = g2[t]; gb_s[512 + HF + t] = b2[t];
    }
    __syncthreads();

    // edge counts, once for all 3 layers (graph topology is layer-invariant)
    if (t < EPG) atomicAdd(&cnt[ed * CSI + (es >> 1)], 1 << ((es & 1) * 16));
    if (t < NPG) atomicAdd(&cnt[t * CSI + (t >> 1)], 1 << ((t & 1) * 16));

    unsigned prevY[8];   // packed bf16 y fragment carried layer->layer

    gat_layer<64, true>(afr0, wt0, al0, ar0, &gb_s[0], out, 0, g, t, prevY,
                        featT, hbuf, cnt, el_s, er_s, rden_s, elmax_i, lnp, lnq, psum4);
    gat_layer<128, false>(nullptr, wt1, al1, ar1, &gb_s[256], out, 1, g, t, prevY,
                          featT, hbuf, cnt, el_s, er_s, rden_s, elmax_i, lnp, lnq, psum4);
    gat_layer<128, false>(nullptr, wt2, al2, ar2, &gb_s[512], out, 2, g, t, prevY,
                          featT, hbuf, cnt, el_s, er_s, rden_s, elmax_i, lnp, lnq, psum4);
}

extern "C" void kernel_launch(void* const* d_in, const int* in_sizes, int n_in,
                              void* d_out, int out_size, void* d_ws, size_t ws_size,
                              hipStream_t stream) {
    const float* x   = (const float*)d_in[0];
    const float* W0  = (const float*)d_in[1];
    const float* al0 = (const float*)d_in[2];
    const float* ar0 = (const float*)d_in[3];
    const float* rW0 = (const float*)d_in[4];
    const float* g0  = (const float*)d_in[5];
    const float* b0  = (const float*)d_in[6];
    const float* W1  = (const float*)d_in[7];
    const float* al1 = (const float*)d_in[8];
    const float* ar1 = (const float*)d_in[9];
    const float* g1  = (const float*)d_in[10];
    const float* b1  = (const float*)d_in[11];
    const float* W2  = (const float*)d_in[12];
    const float* al2 = (const float*)d_in[13];
    const float* ar2 = (const float*)d_in[14];
    const float* g2  = (const float*)d_in[15];
    const float* b2  = (const float*)d_in[16];
    const int* src   = (const int*)d_in[17];
    const int* dst   = (const int*)d_in[18];
    float* out = (float*)d_out;

    unsigned short* wt0 = (unsigned short*)d_ws;
    unsigned short* wt1 = wt0 + 256 * 64;
    unsigned short* wt2 = wt1 + 128 * 128;

    prep_w<<<64, 256, 0, stream>>>(W0, rW0, W1, W2, wt0, wt1, wt2);
    gat3_kernel<<<NGRAPH, 512, 0, stream>>>(
        x, wt0, wt1, wt2, al0, ar0, al1, ar1, al2, ar2,
        g0, b0, g1, b1, g2, b2, src, dst, out);
}

// Round 14
// 252.253 us; speedup vs baseline: 1.0932x; 1.0932x over previous
//
#include <hip/hip_runtime.h>

#define NPG    50
#define HF     128
#define FDIM   64
#define NGRAPH 2048
#define NNODES 102400
#define EPG    400
#define SP     72     // featT row stride (bf16)
#define CSI    36     // cnt row stride (ints), 2 counts/int, 16B-aligned rows
#define HB     136    // hbuf row stride (bf16), 16B-aligned rows

typedef __attribute__((ext_vector_type(8))) short bf16x8;
typedef __attribute__((ext_vector_type(4))) float floatx4;

__device__ __forceinline__ float leaky(float x, float s) { return x >= 0.f ? x : x * s; }
__device__ __forceinline__ unsigned short f2bf(float f) {   // RNE fp32->bf16
    unsigned u = __float_as_uint(f);
    return (unsigned short)((u + 0x7fffu + ((u >> 16) & 1u)) >> 16);
}
__device__ __forceinline__ float bf2f(unsigned short h) {
    return __uint_as_float(((unsigned)h) << 16);
}
__device__ __forceinline__ int fkey(float f) { int b = __float_as_int(f); return b >= 0 ? b : b ^ 0x7fffffff; }
__device__ __forceinline__ float funkey(int k) { return __int_as_float(k >= 0 ? k : k ^ 0x7fffffff); }

// Build transposed bf16 weights: wt0[256][64] = [W0|resW0]^T, wt1/wt2[128][128] = W^T
__global__ void prep_w(const float* __restrict__ W0, const float* __restrict__ rW0,
                       const float* __restrict__ W1, const float* __restrict__ W2,
                       unsigned short* __restrict__ wt0, unsigned short* __restrict__ wt1,
                       unsigned short* __restrict__ wt2) {
    int i = blockIdx.x * 256 + threadIdx.x;
    if (i < 256 * 64) {
        int n = i >> 6, k = i & 63;
        float v = (n < 128) ? W0[k * 128 + n] : rW0[k * 128 + (n - 128)];
        wt0[i] = f2bf(v);
    }
    if (i < 128 * 128) {
        int n = i >> 7, k = i & 127;
        wt1[i] = f2bf(W1[k * 128 + n]);
        wt2[i] = f2bf(W2[k * 128 + n]);
    }
}

// One GAT layer, fully in-block.  hbuf holds (RESW: x@resW0, else: input h) on
// entry to the epilogue, and holds this layer's output y on exit.
// NO float atomics: cross-wave float reductions via uniquely-owned LDS slots +
// fixed-order final sums -> bit-deterministic (graph-replay tripwire safe).
// L0 GEMM runs as two 4-tile passes so the peak MFMA accumulator footprint is
// 16 AGPRs (R12's single-pass acc[8] = 32 AGPRs capped the CU at 2 blocks).
template <int K, bool RESW>
__device__ __forceinline__ void gat_layer(
    const bf16x8* afr_in,                       // RESW: preloaded A-frags
    const unsigned short* __restrict__ Wt,
    const float* __restrict__ al, const float* __restrict__ ar,
    const float* __restrict__ gbl,              // this layer's [g(128)|b(128)] in LDS
    float* __restrict__ out, int layer, int g, int t,
    unsigned short* featT, unsigned short* hbuf, int* cnt,
    float* el_s, float* er_s, float* rden_s, int* elmax_i,
    float* lnp, float* lnq, float* psum4)
{
    const int w = t >> 6, lane = t & 63, quad = lane >> 4, l16 = lane & 15;
    constexpr int KS = K / 32;
    const int mt = w & 3;
    int mrow = mt * 16 + l16;
    if (mrow >= NPG) mrow = NPG - 1;
    const floatx4 zf = {0.f, 0.f, 0.f, 0.f};

    // ---- A-fragments ----
    bf16x8 afr[KS];
    if constexpr (RESW) {
#pragma unroll
        for (int ks = 0; ks < KS; ++ks) afr[ks] = afr_in[ks];
    } else {
#pragma unroll
        for (int ks = 0; ks < KS; ++ks)
            afr[ks] = *(const bf16x8*)&hbuf[mrow * HB + ks * 32 + quad * 8];
    }

    // ---- GEMM via MFMA + el/er + featT/res stores ----
    if constexpr (RESW) {
        // two passes of 4 N-tiles (peak acc = 16 AGPRs).
        // w<4: half h covers exactly head h's 64 cols.  w>=4: res cols -> hbuf.
#pragma unroll
        for (int half = 0; half < 2; ++half) {
            const int nb = (w >> 2) * 8 + half * 4;
            floatx4 acc[4];
#pragma unroll
            for (int nt = 0; nt < 4; ++nt) acc[nt] = zf;
#pragma unroll
            for (int nt = 0; nt < 4; ++nt) {
                const unsigned short* wrow = Wt + (size_t)((nb + nt) * 16 + l16) * K;
#pragma unroll
                for (int ks = 0; ks < KS; ++ks) {
                    bf16x8 b = *(const bf16x8*)(wrow + ks * 32 + quad * 8);
                    acc[nt] = __builtin_amdgcn_mfma_f32_16x16x32_bf16(afr[ks], b, acc[nt], 0, 0, 0);
                }
            }
            if (w < 4) {
                float pe[4] = {0,0,0,0}, pr[4] = {0,0,0,0};
#pragma unroll
                for (int nt = 0; nt < 4; ++nt) {
                    int col = (half * 4 + nt) * 16 + l16;
                    float av = al[col], rv = ar[col];
#pragma unroll
                    for (int r = 0; r < 4; ++r) {
                        pe[r] = fmaf(acc[nt][r], av, pe[r]);
                        pr[r] = fmaf(acc[nt][r], rv, pr[r]);
                    }
                }
#pragma unroll
                for (int m = 1; m <= 8; m <<= 1) {
#pragma unroll
                    for (int r = 0; r < 4; ++r) {
                        pe[r] += __shfl_xor(pe[r], m, 64);
                        pr[r] += __shfl_xor(pr[r], m, 64);
                    }
                }
                if (l16 == 0) {
#pragma unroll
                    for (int r = 0; r < 4; ++r) {
                        int row = mt * 16 + quad * 4 + r;
                        el_s[half * 64 + row] = pe[r];
                        er_s[half * 64 + row] = pr[r];
                        atomicMax(&elmax_i[half], fkey(pe[r]));  // int max: exact
                    }
                }
            }
#pragma unroll
            for (int nt = 0; nt < 4; ++nt) {
                int n = (nb + nt) * 16 + l16;
                if (n < HF) {
                    unsigned lo = (unsigned)f2bf(acc[nt][0]) | ((unsigned)f2bf(acc[nt][1]) << 16);
                    unsigned hi = (unsigned)f2bf(acc[nt][2]) | ((unsigned)f2bf(acc[nt][3]) << 16);
                    uint2 pk = {lo, hi};
                    *(uint2*)&featT[n * SP + mt * 16 + quad * 4] = pk;
                } else {
#pragma unroll
                    for (int r = 0; r < 4; ++r) {
                        int d = mt * 16 + quad * 4 + r;
                        if (d < NPG) hbuf[d * HB + (n - HF)] = f2bf(acc[nt][r]);
                    }
                }
            }
        }
    } else {
        const int ntbase = (w >> 2) * 4;
        floatx4 acc[4];
#pragma unroll
        for (int nt = 0; nt < 4; ++nt) acc[nt] = zf;
#pragma unroll
        for (int nt = 0; nt < 4; ++nt) {
            const unsigned short* wrow = Wt + (size_t)((ntbase + nt) * 16 + l16) * K;
#pragma unroll
            for (int ks = 0; ks < KS; ++ks) {
                bf16x8 b = *(const bf16x8*)(wrow + ks * 32 + quad * 8);
                acc[nt] = __builtin_amdgcn_mfma_f32_16x16x32_bf16(afr[ks], b, acc[nt], 0, 0, 0);
            }
        }
        {
            float pe[4] = {0,0,0,0}, pr[4] = {0,0,0,0};
#pragma unroll
            for (int nt = 0; nt < 4; ++nt) {
                int col = (ntbase + nt) * 16 + l16;
                float av = al[col], rv = ar[col];
#pragma unroll
                for (int r = 0; r < 4; ++r) {
                    pe[r] = fmaf(acc[nt][r], av, pe[r]);
                    pr[r] = fmaf(acc[nt][r], rv, pr[r]);
                }
            }
#pragma unroll
            for (int m = 1; m <= 8; m <<= 1) {
#pragma unroll
                for (int r = 0; r < 4; ++r) {
                    pe[r] += __shfl_xor(pe[r], m, 64);
                    pr[r] += __shfl_xor(pr[r], m, 64);
                }
            }
            if (l16 == 0) {
                int hd = w >> 2;
#pragma unroll
                for (int r = 0; r < 4; ++r) {
                    int row = mt * 16 + quad * 4 + r;
                    el_s[hd * 64 + row] = pe[r];
                    er_s[hd * 64 + row] = pr[r];
                    atomicMax(&elmax_i[hd], fkey(pe[r]));
                }
            }
        }
#pragma unroll
        for (int nt = 0; nt < 4; ++nt) {
            int n = (ntbase + nt) * 16 + l16;
            unsigned lo = (unsigned)f2bf(acc[nt][0]) | ((unsigned)f2bf(acc[nt][1]) << 16);
            unsigned hi = (unsigned)f2bf(acc[nt][2]) | ((unsigned)f2bf(acc[nt][3]) << 16);
            uint2 pk = {lo, hi};
            *(uint2*)&featT[n * SP + mt * 16 + quad * 4] = pk;
        }
    }
    __syncthreads();   // B1

    // ---- exp A-frag + aggregation MFMA + epilogue ----
    const int hd = w >> 2, amt = w & 3;
    const int d = amt * 16 + l16;    // A-frag dst row (>=NPG rows: cnt is zero)

    // max_s leaky(el+er) = leaky(max_s el + er)  (leaky monotone)
    const float erd = er_s[hd * 64 + d];
    const float md = leaky(funkey(elmax_i[hd]) + erd, 0.2f);
    float elv[16];
    *(float4*)&elv[0]  = *(const float4*)&el_s[hd * 64 + quad * 8];
    *(float4*)&elv[4]  = *(const float4*)&el_s[hd * 64 + quad * 8 + 4];
    *(float4*)&elv[8]  = *(const float4*)&el_s[hd * 64 + 32 + quad * 8];
    *(float4*)&elv[12] = *(const float4*)&el_s[hd * 64 + 32 + quad * 8 + 4];
    int4 ci0 = *(const int4*)&cnt[d * CSI + quad * 4];
    int4 ci1 = *(const int4*)&cnt[d * CSI + 16 + quad * 4];

    bf16x8 ap[2];
    float rowsum = 0.f;
#pragma unroll
    for (int ks = 0; ks < 2; ++ks) {
        const int* ci = ks ? (const int*)&ci1 : (const int*)&ci0;
        bf16x8 a;
#pragma unroll
        for (int j = 0; j < 8; ++j) {
            float e = elv[ks * 8 + j] + erd;
            e = fmaxf(e, 0.2f * e);                 // leaky (slope < 1)
            float p = __expf(e - md);
            int c = (ci[j >> 1] >> ((j & 1) * 16)) & 0xffff;
            unsigned short xb = f2bf((float)c * p); // c==0 -> exact 0
            a[j] = (short)xb;
            rowsum += bf2f(xb);
        }
        ap[ks] = a;
    }
    rowsum += __shfl_xor(rowsum, 16, 64);
    rowsum += __shfl_xor(rowsum, 32, 64);
    if (quad == 0) rden_s[hd * 64 + d] = 1.f / fmaxf(rowsum, 1e-30f);

    floatx4 ag[4];
#pragma unroll
    for (int nt = 0; nt < 4; ++nt) ag[nt] = zf;
#pragma unroll
    for (int nt = 0; nt < 4; ++nt) {
        const unsigned short* fr = &featT[(hd * 64 + nt * 16 + l16) * SP];
#pragma unroll
        for (int ks = 0; ks < 2; ++ks) {
            bf16x8 b = *(const bf16x8*)(fr + ks * 32 + quad * 8);
            ag[nt] = __builtin_amdgcn_mfma_f32_16x16x32_bf16(ap[ks], b, ag[nt], 0, 0, 0);
        }
    }

    // scale + residual; LN partials into uniquely-owned slots (deterministic)
    float s1[4] = {0,0,0,0}, s2[4] = {0,0,0,0};
#pragma unroll
    for (int r = 0; r < 4; ++r) {
        int dd = amt * 16 + quad * 4 + r;
        float rdv = rden_s[hd * 64 + (dd < 64 ? dd : 63)];
        int dc = dd < NPG ? dd : NPG - 1;
#pragma unroll
        for (int nt = 0; nt < 4; ++nt) {
            int col = hd * 64 + nt * 16 + l16;
            float vv = fmaf(ag[nt][r], rdv, bf2f(hbuf[dc * HB + col]));
            ag[nt][r] = vv;
            s1[r] += vv;
            s2[r] = fmaf(vv, vv, s2[r]);
        }
    }
#pragma unroll
    for (int m = 1; m <= 8; m <<= 1) {
#pragma unroll
        for (int r = 0; r < 4; ++r) {
            s1[r] += __shfl_xor(s1[r], m, 64);
            s2[r] += __shfl_xor(s2[r], m, 64);
        }
    }
    if (l16 == 0) {
#pragma unroll
        for (int r = 0; r < 4; ++r) {
            int dd = amt * 16 + quad * 4 + r;   // slot [hd][dd]: single writer
            lnp[hd * 64 + dd] = s1[r];
            lnq[hd * 64 + dd] = s2[r];
        }
    }
    __syncthreads();   // B2: LN slots written; hbuf/featT reads done

    // re-arm elmax for the next layer (reads finished at B2, writes after B3)
    if (t < 2) elmax_i[t] = (int)0x80000000;

    // normalize + affine + leaky -> y into hbuf; readout partials from fp32 y
    float part[4] = {0, 0, 0, 0};
#pragma unroll
    for (int r = 0; r < 4; ++r) {
        int dd = amt * 16 + quad * 4 + r;
        if (dd < NPG) {
            float mus = lnp[dd] + lnp[64 + dd];         // fixed order: head0 + head1
            float sqs = lnq[dd] + lnq[64 + dd];
            float mu = mus * (1.f / HF);
            float rs = rsqrtf(sqs * (1.f / HF) - mu * mu + 1e-5f);
#pragma unroll
            for (int nt = 0; nt < 4; ++nt) {
                int col = hd * 64 + nt * 16 + l16;
                float y = (ag[nt][r] - mu) * rs * gbl[col] + gbl[HF + col];
                y = leaky(y, 0.1f);
                hbuf[dd * HB + col] = f2bf(y);
                part[nt] += y;
            }
        }
    }
    // sum part over quads in-wave; slot [amt][col]: single writer per slot
#pragma unroll
    for (int nt = 0; nt < 4; ++nt) {
        part[nt] += __shfl_xor(part[nt], 16, 64);
        part[nt] += __shfl_xor(part[nt], 32, 64);
    }
    if (quad == 0) {
#pragma unroll
        for (int nt = 0; nt < 4; ++nt)
            psum4[amt * HF + hd * 64 + nt * 16 + l16] = part[nt];
    }
    __syncthreads();   // B3: y visible (next layer A-frags), psum4 complete

    if (t < FDIM) {
        float s = 0.f;
#pragma unroll
        for (int a4 = 0; a4 < 4; ++a4)                   // fixed summation order
            s += psum4[a4 * HF + t] + psum4[a4 * HF + t + FDIM];
        out[(size_t)g * (3 * FDIM) + layer * FDIM + t] = leaky(s * (1.f / (2 * NPG)), 0.1f);
    }
    // no re-zero needed: lnp/lnq/psum4 slots are fully overwritten next layer
}

// One block per graph runs all 3 layers (edges never cross graphs -> no grid
// sync needed; h carried in LDS, never touches HBM).
// (512,4): no register cap pressure -- caps of 85 or fewer regs spilled
// (R7/R10/R13, +40..160 MB HBM each).  Occupancy gain comes from the L0
// two-pass GEMM cutting peak AGPRs 32->16 instead.
__global__ __launch_bounds__(512, 4) void gat3_kernel(
    const float* __restrict__ x,
    const unsigned short* __restrict__ wt0,
    const unsigned short* __restrict__ wt1,
    const unsigned short* __restrict__ wt2,
    const float* __restrict__ al0, const float* __restrict__ ar0,
    const float* __restrict__ al1, const float* __restrict__ ar1,
    const float* __restrict__ al2, const float* __restrict__ ar2,
    const float* __restrict__ g0, const float* __restrict__ b0,
    const float* __restrict__ g1, const float* __restrict__ b1,
    const float* __restrict__ g2, const float* __restrict__ b2,
    const int* __restrict__ src, const int* __restrict__ dst,
    float* __restrict__ out)
{
    __shared__ unsigned short featT[HF * SP];   // 18432 B
    __shared__ unsigned short hbuf[NPG * HB];   // 13600 B (res/h/y carrier)
    __shared__ int cnt[64 * CSI];               // 9216 B, rows 50..63 stay zero
    __shared__ float el_s[128], er_s[128], rden_s[128];
    __shared__ int elmax_i[2];
    __shared__ float lnp[128], lnq[128];        // LN partials [head][row]
    __shared__ float psum4[4 * HF];             // readout partials [amt][col]
    __shared__ float gb_s[3 * 2 * HF];          // 3 layers x [g|b]

    const int g = blockIdx.x, t = threadIdx.x;
    const int nbase = g * NPG;
    const int w = t >> 6, lane = t & 63, quad = lane >> 4, l16 = lane & 15;

    // independent global loads at cycle 0
    int es = 0, ed = 0;
    if (t < EPG) { es = src[g * EPG + t] - nbase; ed = dst[g * EPG + t] - nbase; }

    // L0 A-fragments from global fp32 x (early issue)
    const int mt = w & 3;
    int mrow = mt * 16 + l16;
    if (mrow >= NPG) mrow = NPG - 1;
    bf16x8 afr0[2];
    {
        const float* hrow = x + (size_t)(nbase + mrow) * 64;
#pragma unroll
        for (int ks = 0; ks < 2; ++ks) {
            int k0 = ks * 32 + quad * 8;
            float4 p0 = *(const float4*)(hrow + k0);
            float4 p1 = *(const float4*)(hrow + k0 + 4);
            bf16x8 a;
            a[0] = (short)f2bf(p0.x); a[1] = (short)f2bf(p0.y);
            a[2] = (short)f2bf(p0.z); a[3] = (short)f2bf(p0.w);
            a[4] = (short)f2bf(p1.x); a[5] = (short)f2bf(p1.y);
            a[6] = (short)f2bf(p1.z); a[7] = (short)f2bf(p1.w);
            afr0[ks] = a;
        }
    }

    // init
    for (int i = t; i < 64 * CSI; i += 512) cnt[i] = 0;
    if (t < 2) elmax_i[t] = (int)0x80000000;
    if (t < HF) {
        gb_s[t] = g0[t];       gb_s[HF + t] = b0[t];
        gb_s[256 + t] = g1[t]; gb_s[256 + HF + t] = b1[t];
        gb_s[512 + t] = g2[t]; gb_s[512 + HF + t] = b2[t];
    }
    __syncthreads();

    // edge counts, once for all 3 layers (graph topology is layer-invariant)
    if (t < EPG) atomicAdd(&cnt[ed * CSI + (es >> 1)], 1 << ((es & 1) * 16));
    if (t < NPG) atomicAdd(&cnt[t * CSI + (t >> 1)], 1 << ((t & 1) * 16));

    gat_layer<64, true>(afr0, wt0, al0, ar0, &gb_s[0], out, 0, g, t,
                        featT, hbuf, cnt, el_s, er_s, rden_s, elmax_i, lnp, lnq, psum4);
    gat_layer<128, false>(nullptr, wt1, al1, ar1, &gb_s[256], out, 1, g, t,
                          featT, hbuf, cnt, el_s, er_s, rden_s, elmax_i, lnp, lnq, psum4);
    gat_layer<128, false>(nullptr, wt2, al2, ar2, &gb_s[512], out, 2, g, t,
                          featT, hbuf, cnt, el_s, er_s, rden_s, elmax_i, lnp, lnq, psum4);
}

extern "C" void kernel_launch(void* const* d_in, const int* in_sizes, int n_in,
                              void* d_out, int out_size, void* d_ws, size_t ws_size,
                              hipStream_t stream) {
    const float* x   = (const float*)d_in[0];
    const float* W0  = (const float*)d_in[1];
    const float* al0 = (const float*)d_in[2];
    const float* ar0 = (const float*)d_in[3];
    const float* rW0 = (const float*)d_in[4];
    const float* g0  = (const float*)d_in[5];
    const float* b0  = (const float*)d_in[6];
    const float* W1  = (const float*)d_in[7];
    const float* al1 = (const float*)d_in[8];
    const float* ar1 = (const float*)d_in[9];
    const float* g1  = (const float*)d_in[10];
    const float* b1  = (const float*)d_in[11];
    const float* W2  = (const float*)d_in[12];
    const float* al2 = (const float*)d_in[13];
    const float* ar2 = (const float*)d_in[14];
    const float* g2  = (const float*)d_in[15];
    const float* b2  = (const float*)d_in[16];
    const int* src   = (const int*)d_in[17];
    const int* dst   = (const int*)d_in[18];
    float* out = (float*)d_out;

    unsigned short* wt0 = (unsigned short*)d_ws;
    unsigned short* wt1 = wt0 + 256 * 64;
    unsigned short* wt2 = wt1 + 128 * 128;

    prep_w<<<64, 256, 0, stream>>>(W0, rW0, W1, W2, wt0, wt1, wt2);
    gat3_kernel<<<NGRAPH, 512, 0, stream>>>(
        x, wt0, wt1, wt2, al0, ar0, al1, ar1, al2, ar2,
        g0, b0, g1, b1, g2, b2, src, dst, out);
}

// Round 15
// 251.608 us; speedup vs baseline: 1.0960x; 1.0026x over previous
//
#include <hip/hip_runtime.h>

#define NPG    50
#define HF     128
#define FDIM   64
#define NGRAPH 2048
#define NNODES 102400
#define EPG    400
#define SP     72     // featT row stride (bf16)
#define CSI    36     // cnt row stride (ints), 2 counts/int, 16B-aligned rows
#define HB     136    // hbuf row stride (bf16), 16B-aligned rows

typedef __attribute__((ext_vector_type(8))) short bf16x8;
typedef __attribute__((ext_vector_type(4))) float floatx4;
typedef __bf16 bfv2 __attribute__((ext_vector_type(2)));

__device__ __forceinline__ float leaky(float x, float s) { return x >= 0.f ? x : x * s; }

// fp32->bf16 RNE via native __bf16 cast (gfx950: v_cvt_pk_bf16_f32); packed
// pair = 1 inst for 2 values (manual bit-trick RNE was 4 inst per value).
__device__ __forceinline__ unsigned short f2bf(float f) {
    __bf16 b = (__bf16)f;
    unsigned short u;
    __builtin_memcpy(&u, &b, 2);
    return u;
}
__device__ __forceinline__ unsigned f2bfpk(float a, float b) {
    bfv2 v;
    v[0] = (__bf16)a;
    v[1] = (__bf16)b;
    unsigned u;
    __builtin_memcpy(&u, &v, 4);
    return u;
}
__device__ __forceinline__ float bf2f(unsigned short h) {
    return __uint_as_float(((unsigned)h) << 16);
}
__device__ __forceinline__ int fkey(float f) { int b = __float_as_int(f); return b >= 0 ? b : b ^ 0x7fffffff; }
__device__ __forceinline__ float funkey(int k) { return __int_as_float(k >= 0 ? k : k ^ 0x7fffffff); }

// Build transposed bf16 weights: wt0[256][64] = [W0|resW0]^T, wt1/wt2[128][128] = W^T
__global__ void prep_w(const float* __restrict__ W0, const float* __restrict__ rW0,
                       const float* __restrict__ W1, const float* __restrict__ W2,
                       unsigned short* __restrict__ wt0, unsigned short* __restrict__ wt1,
                       unsigned short* __restrict__ wt2) {
    int i = blockIdx.x * 256 + threadIdx.x;
    if (i < 256 * 64) {
        int n = i >> 6, k = i & 63;
        float v = (n < 128) ? W0[k * 128 + n] : rW0[k * 128 + (n - 128)];
        wt0[i] = f2bf(v);
    }
    if (i < 128 * 128) {
        int n = i >> 7, k = i & 127;
        wt1[i] = f2bf(W1[k * 128 + n]);
        wt2[i] = f2bf(W2[k * 128 + n]);
    }
}

// One GAT layer, fully in-block.  hbuf holds (RESW: x@resW0, else: input h) on
// entry to the epilogue, and holds this layer's output y on exit.
// NO float atomics: cross-wave float reductions via uniquely-owned LDS slots +
// fixed-order final sums -> bit-deterministic (graph-replay tripwire safe).
template <int K, bool RESW>
__device__ __forceinline__ void gat_layer(
    const bf16x8* afr_in,                       // RESW: preloaded A-frags
    const unsigned short* __restrict__ Wt,
    const float* __restrict__ al, const float* __restrict__ ar,
    const float* __restrict__ gbl,              // this layer's [g(128)|b(128)] in LDS
    float* __restrict__ out, int layer, int g, int t,
    unsigned short* featT, unsigned short* hbuf, int* cnt,
    float* el_s, float* er_s, float* rden_s, int* elmax_i,
    float* lnp, float* lnq, float* psum4)
{
    const int w = t >> 6, lane = t & 63, quad = lane >> 4, l16 = lane & 15;
    constexpr int KS = K / 32;
    const int mt = w & 3;
    int mrow = mt * 16 + l16;
    if (mrow >= NPG) mrow = NPG - 1;
    const floatx4 zf = {0.f, 0.f, 0.f, 0.f};

    // ---- A-fragments ----
    bf16x8 afr[KS];
    if constexpr (RESW) {
#pragma unroll
        for (int ks = 0; ks < KS; ++ks) afr[ks] = afr_in[ks];
    } else {
#pragma unroll
        for (int ks = 0; ks < KS; ++ks)
            afr[ks] = *(const bf16x8*)&hbuf[mrow * HB + ks * 32 + quad * 8];
    }

    // ---- GEMM via MFMA + el/er + featT/res stores ----
    if constexpr (RESW) {
        // two SEQUENTIAL passes of 4 N-tiles: peak acc = 16 AGPRs.
        // unroll 1 is load-bearing -- full unroll re-fuses to acc[8]=32 AGPRs
        // and drops the CU to 2 blocks (R14).
#pragma unroll 1
        for (int half = 0; half < 2; ++half) {
            const int nb = (w >> 2) * 8 + half * 4;
            floatx4 acc[4];
#pragma unroll
            for (int nt = 0; nt < 4; ++nt) acc[nt] = zf;
#pragma unroll
            for (int nt = 0; nt < 4; ++nt) {
                const unsigned short* wrow = Wt + (size_t)((nb + nt) * 16 + l16) * K;
#pragma unroll
                for (int ks = 0; ks < KS; ++ks) {
                    bf16x8 b = *(const bf16x8*)(wrow + ks * 32 + quad * 8);
                    acc[nt] = __builtin_amdgcn_mfma_f32_16x16x32_bf16(afr[ks], b, acc[nt], 0, 0, 0);
                }
            }
            if (w < 4) {
                float pe[4] = {0,0,0,0}, pr[4] = {0,0,0,0};
#pragma unroll
                for (int nt = 0; nt < 4; ++nt) {
                    int col = (half * 4 + nt) * 16 + l16;
                    float av = al[col], rv = ar[col];
#pragma unroll
                    for (int r = 0; r < 4; ++r) {
                        pe[r] = fmaf(acc[nt][r], av, pe[r]);
                        pr[r] = fmaf(acc[nt][r], rv, pr[r]);
                    }
                }
#pragma unroll
                for (int m = 1; m <= 8; m <<= 1) {
#pragma unroll
                    for (int r = 0; r < 4; ++r) {
                        pe[r] += __shfl_xor(pe[r], m, 64);
                        pr[r] += __shfl_xor(pr[r], m, 64);
                    }
                }
                if (l16 == 0) {
#pragma unroll
                    for (int r = 0; r < 4; ++r) {
                        int row = mt * 16 + quad * 4 + r;
                        el_s[half * 64 + row] = pe[r];
                        er_s[half * 64 + row] = pr[r];
                        atomicMax(&elmax_i[half], fkey(pe[r]));  // int max: exact
                    }
                }
            }
#pragma unroll
            for (int nt = 0; nt < 4; ++nt) {
                int n = (nb + nt) * 16 + l16;
                if (n < HF) {
                    uint2 pk = {f2bfpk(acc[nt][0], acc[nt][1]),
                                f2bfpk(acc[nt][2], acc[nt][3])};
                    *(uint2*)&featT[n * SP + mt * 16 + quad * 4] = pk;
                } else {
#pragma unroll
                    for (int r = 0; r < 4; ++r) {
                        int d = mt * 16 + quad * 4 + r;
                        if (d < NPG) hbuf[d * HB + (n - HF)] = f2bf(acc[nt][r]);
                    }
                }
            }
        }
    } else {
        const int ntbase = (w >> 2) * 4;
        floatx4 acc[4];
#pragma unroll
        for (int nt = 0; nt < 4; ++nt) acc[nt] = zf;
#pragma unroll
        for (int nt = 0; nt < 4; ++nt) {
            const unsigned short* wrow = Wt + (size_t)((ntbase + nt) * 16 + l16) * K;
#pragma unroll
            for (int ks = 0; ks < KS; ++ks) {
                bf16x8 b = *(const bf16x8*)(wrow + ks * 32 + quad * 8);
                acc[nt] = __builtin_amdgcn_mfma_f32_16x16x32_bf16(afr[ks], b, acc[nt], 0, 0, 0);
            }
        }
        {
            float pe[4] = {0,0,0,0}, pr[4] = {0,0,0,0};
#pragma unroll
            for (int nt = 0; nt < 4; ++nt) {
                int col = (ntbase + nt) * 16 + l16;
                float av = al[col], rv = ar[col];
#pragma unroll
                for (int r = 0; r < 4; ++r) {
                    pe[r] = fmaf(acc[nt][r], av, pe[r]);
                    pr[r] = fmaf(acc[nt][r], rv, pr[r]);
                }
            }
#pragma unroll
            for (int m = 1; m <= 8; m <<= 1) {
#pragma unroll
                for (int r = 0; r < 4; ++r) {
                    pe[r] += __shfl_xor(pe[r], m, 64);
                    pr[r] += __shfl_xor(pr[r], m, 64);
                }
            }
            if (l16 == 0) {
                int hd = w >> 2;
#pragma unroll
                for (int r = 0; r < 4; ++r) {
                    int row = mt * 16 + quad * 4 + r;
                    el_s[hd * 64 + row] = pe[r];
                    er_s[hd * 64 + row] = pr[r];
                    atomicMax(&elmax_i[hd], fkey(pe[r]));
                }
            }
        }
#pragma unroll
        for (int nt = 0; nt < 4; ++nt) {
            int n = (ntbase + nt) * 16 + l16;
            uint2 pk = {f2bfpk(acc[nt][0], acc[nt][1]),
                        f2bfpk(acc[nt][2], acc[nt][3])};
            *(uint2*)&featT[n * SP + mt * 16 + quad * 4] = pk;
        }
    }
    __syncthreads();   // B1

    // ---- exp A-frag + aggregation MFMA + epilogue ----
    const int hd = w >> 2, amt = w & 3;
    const int d = amt * 16 + l16;    // A-frag dst row (>=NPG rows: cnt is zero)

    // max_s leaky(el+er) = leaky(max_s el + er)  (leaky monotone)
    const float erd = er_s[hd * 64 + d];
    const float md = leaky(funkey(elmax_i[hd]) + erd, 0.2f);
    float elv[16];
    *(float4*)&elv[0]  = *(const float4*)&el_s[hd * 64 + quad * 8];
    *(float4*)&elv[4]  = *(const float4*)&el_s[hd * 64 + quad * 8 + 4];
    *(float4*)&elv[8]  = *(const float4*)&el_s[hd * 64 + 32 + quad * 8];
    *(float4*)&elv[12] = *(const float4*)&el_s[hd * 64 + 32 + quad * 8 + 4];
    int4 ci0 = *(const int4*)&cnt[d * CSI + quad * 4];
    int4 ci1 = *(const int4*)&cnt[d * CSI + 16 + quad * 4];

    bf16x8 ap[2];
    float rowsum = 0.f;
#pragma unroll
    for (int ks = 0; ks < 2; ++ks) {
        const int* ci = ks ? (const int*)&ci1 : (const int*)&ci0;
        unsigned au[4];
#pragma unroll
        for (int jp = 0; jp < 4; ++jp) {                // pairs (2*jp, 2*jp+1)
            float e0 = elv[ks * 8 + 2 * jp] + erd;
            float e1 = elv[ks * 8 + 2 * jp + 1] + erd;
            e0 = fmaxf(e0, 0.2f * e0);                  // leaky (slope < 1)
            e1 = fmaxf(e1, 0.2f * e1);
            float p0 = __expf(e0 - md);
            float p1 = __expf(e1 - md);
            int c0 = ci[jp] & 0xffff;
            int c1 = ((unsigned)ci[jp]) >> 16;
            unsigned pk = f2bfpk((float)c0 * p0, (float)c1 * p1);  // c==0 -> exact 0
            au[jp] = pk;
            rowsum += __uint_as_float(pk << 16) + __uint_as_float(pk & 0xffff0000u);
        }
        __builtin_memcpy(&ap[ks], au, 16);
    }
    rowsum += __shfl_xor(rowsum, 16, 64);
    rowsum += __shfl_xor(rowsum, 32, 64);
    if (quad == 0) rden_s[hd * 64 + d] = 1.f / fmaxf(rowsum, 1e-30f);

    floatx4 ag[4];
#pragma unroll
    for (int nt = 0; nt < 4; ++nt) ag[nt] = zf;
#pragma unroll
    for (int nt = 0; nt < 4; ++nt) {
        const unsigned short* fr = &featT[(hd * 64 + nt * 16 + l16) * SP];
#pragma unroll
        for (int ks = 0; ks < 2; ++ks) {
            bf16x8 b = *(const bf16x8*)(fr + ks * 32 + quad * 8);
            ag[nt] = __builtin_amdgcn_mfma_f32_16x16x32_bf16(ap[ks], b, ag[nt], 0, 0, 0);
        }
    }

    // scale + residual; LN partials into uniquely-owned slots (deterministic)
    float s1[4] = {0,0,0,0}, s2[4] = {0,0,0,0};
#pragma unroll
    for (int r = 0; r < 4; ++r) {
        int dd = amt * 16 + quad * 4 + r;
        float rdv = rden_s[hd * 64 + (dd < 64 ? dd : 63)];
        int dc = dd < NPG ? dd : NPG - 1;
#pragma unroll
        for (int nt = 0; nt < 4; ++nt) {
            int col = hd * 64 + nt * 16 + l16;
            float vv = fmaf(ag[nt][r], rdv, bf2f(hbuf[dc * HB + col]));
            ag[nt][r] = vv;
            s1[r] += vv;
            s2[r] = fmaf(vv, vv, s2[r]);
        }
    }
#pragma unroll
    for (int m = 1; m <= 8; m <<= 1) {
#pragma unroll
        for (int r = 0; r < 4; ++r) {
            s1[r] += __shfl_xor(s1[r], m, 64);
            s2[r] += __shfl_xor(s2[r], m, 64);
        }
    }
    if (l16 == 0) {
#pragma unroll
        for (int r = 0; r < 4; ++r) {
            int dd = amt * 16 + quad * 4 + r;   // slot [hd][dd]: single writer
            lnp[hd * 64 + dd] = s1[r];
            lnq[hd * 64 + dd] = s2[r];
        }
    }
    __syncthreads();   // B2: LN slots written; hbuf/featT reads done

    // re-arm elmax for the next layer (reads finished at B2, writes after B3)
    if (t < 2) elmax_i[t] = (int)0x80000000;

    // normalize + affine + leaky -> y into hbuf; readout partials from fp32 y
    float part[4] = {0, 0, 0, 0};
#pragma unroll
    for (int r = 0; r < 4; ++r) {
        int dd = amt * 16 + quad * 4 + r;
        if (dd < NPG) {
            float mus = lnp[dd] + lnp[64 + dd];         // fixed order: head0 + head1
            float sqs = lnq[dd] + lnq[64 + dd];
            float mu = mus * (1.f / HF);
            float rs = rsqrtf(sqs * (1.f / HF) - mu * mu + 1e-5f);
            float y4[4];
#pragma unroll
            for (int nt = 0; nt < 4; ++nt) {
                int col = hd * 64 + nt * 16 + l16;
                float y = (ag[nt][r] - mu) * rs * gbl[col] + gbl[HF + col];
                y = leaky(y, 0.1f);
                y4[nt] = y;
                part[nt] += y;
            }
            unsigned pk01 = f2bfpk(y4[0], y4[1]);
            unsigned pk23 = f2bfpk(y4[2], y4[3]);
            int base = dd * HB + hd * 64 + l16;
            hbuf[base]      = (unsigned short)(pk01 & 0xffffu);
            hbuf[base + 16] = (unsigned short)(pk01 >> 16);
            hbuf[base + 32] = (unsigned short)(pk23 & 0xffffu);
            hbuf[base + 48] = (unsigned short)(pk23 >> 16);
        }
    }
    // sum part over quads in-wave; slot [amt][col]: single writer per slot
#pragma unroll
    for (int nt = 0; nt < 4; ++nt) {
        part[nt] += __shfl_xor(part[nt], 16, 64);
        part[nt] += __shfl_xor(part[nt], 32, 64);
    }
    if (quad == 0) {
#pragma unroll
        for (int nt = 0; nt < 4; ++nt)
            psum4[amt * HF + hd * 64 + nt * 16 + l16] = part[nt];
    }
    __syncthreads();   // B3: y visible (next layer A-frags), psum4 complete

    if (t < FDIM) {
        float s = 0.f;
#pragma unroll
        for (int a4 = 0; a4 < 4; ++a4)                   // fixed summation order
            s += psum4[a4 * HF + t] + psum4[a4 * HF + t + FDIM];
        out[(size_t)g * (3 * FDIM) + layer * FDIM + t] = leaky(s * (1.f / (2 * NPG)), 0.1f);
    }
    // no re-zero needed: lnp/lnq/psum4 slots are fully overwritten next layer
}

// One block per graph runs all 3 layers (edges never cross graphs -> no grid
// sync needed; h carried in LDS, never touches HBM).
// (512,4): no register cap -- caps of <=85 regs spilled (R7/R10/R13,
// +40..160 MB HBM each).  Occupancy comes from keeping natural allocation
// low: two-pass L0 GEMM (unroll 1) + packed bf16 converts.
__global__ __launch_bounds__(512, 4) void gat3_kernel(
    const float* __restrict__ x,
    const unsigned short* __restrict__ wt0,
    const unsigned short* __restrict__ wt1,
    const unsigned short* __restrict__ wt2,
    const float* __restrict__ al0, const float* __restrict__ ar0,
    const float* __restrict__ al1, const float* __restrict__ ar1,
    const float* __restrict__ al2, const float* __restrict__ ar2,
    const float* __restrict__ g0, const float* __restrict__ b0,
    const float* __restrict__ g1, const float* __restrict__ b1,
    const float* __restrict__ g2, const float* __restrict__ b2,
    const int* __restrict__ src, const int* __restrict__ dst,
    float* __restrict__ out)
{
    __shared__ unsigned short featT[HF * SP];   // 18432 B
    __shared__ unsigned short hbuf[NPG * HB];   // 13600 B (res/h/y carrier)
    __shared__ int cnt[64 * CSI];               // 9216 B, rows 50..63 stay zero
    __shared__ float el_s[128], er_s[128], rden_s[128];
    __shared__ int elmax_i[2];
    __shared__ float lnp[128], lnq[128];        // LN partials [head][row]
    __shared__ float psum4[4 * HF];             // readout partials [amt][col]
    __shared__ float gb_s[3 * 2 * HF];          // 3 layers x [g|b]

    const int g = blockIdx.x, t = threadIdx.x;
    const int nbase = g * NPG;
    const int w = t >> 6, lane = t & 63, quad = lane >> 4, l16 = lane & 15;

    // independent global loads at cycle 0
    int es = 0, ed = 0;
    if (t < EPG) { es = src[g * EPG + t] - nbase; ed = dst[g * EPG + t] - nbase; }

    // L0 A-fragments from global fp32 x (early issue)
    const int mt = w & 3;
    int mrow = mt * 16 + l16;
    if (mrow >= NPG) mrow = NPG - 1;
    bf16x8 afr0[2];
    {
        const float* hrow = x + (size_t)(nbase + mrow) * 64;
#pragma unroll
        for (int ks = 0; ks < 2; ++ks) {
            int k0 = ks * 32 + quad * 8;
            float4 p0 = *(const float4*)(hrow + k0);
            float4 p1 = *(const float4*)(hrow + k0 + 4);
            unsigned au[4] = {f2bfpk(p0.x, p0.y), f2bfpk(p0.z, p0.w),
                              f2bfpk(p1.x, p1.y), f2bfpk(p1.z, p1.w)};
            __builtin_memcpy(&afr0[ks], au, 16);
        }
    }

    // init
    for (int i = t; i < 64 * CSI; i += 512) cnt[i] = 0;
    if (t < 2) elmax_i[t] = (int)0x80000000;
    if (t < HF) {
        gb_s[t] = g0[t];       gb_s[HF + t] = b0[t];
        gb_s[256 + t] = g1[t]; gb_s[256 + HF + t] = b1[t];
        gb_s[512 + t] = g2[t]; gb_s[512 + HF + t] = b2[t];
    }
    __syncthreads();

    // edge counts, once for all 3 layers (graph topology is layer-invariant)
    if (t < EPG) atomicAdd(&cnt[ed * CSI + (es >> 1)], 1 << ((es & 1) * 16));
    if (t < NPG) atomicAdd(&cnt[t * CSI + (t >> 1)], 1 << ((t & 1) * 16));

    gat_layer<64, true>(afr0, wt0, al0, ar0, &gb_s[0], out, 0, g, t,
                        featT, hbuf, cnt, el_s, er_s, rden_s, elmax_i, lnp, lnq, psum4);
    gat_layer<128, false>(nullptr, wt1, al1, ar1, &gb_s[256], out, 1, g, t,
                          featT, hbuf, cnt, el_s, er_s, rden_s, elmax_i, lnp, lnq, psum4);
    gat_layer<128, false>(nullptr, wt2, al2, ar2, &gb_s[512], out, 2, g, t,
                          featT, hbuf, cnt, el_s, er_s, rden_s, elmax_i, lnp, lnq, psum4);
}

extern "C" void kernel_launch(void* const* d_in, const int* in_sizes, int n_in,
                              void* d_out, int out_size, void* d_ws, size_t ws_size,
                              hipStream_t stream) {
    const float* x   = (const float*)d_in[0];
    const float* W0  = (const float*)d_in[1];
    const float* al0 = (const float*)d_in[2];
    const float* ar0 = (const float*)d_in[3];
    const float* rW0 = (const float*)d_in[4];
    const float* g0  = (const float*)d_in[5];
    const float* b0  = (const float*)d_in[6];
    const float* W1  = (const float*)d_in[7];
    const float* al1 = (const float*)d_in[8];
    const float* ar1 = (const float*)d_in[9];
    const float* g1  = (const float*)d_in[10];
    const float* b1  = (const float*)d_in[11];
    const float* W2  = (const float*)d_in[12];
    const float* al2 = (const float*)d_in[13];
    const float* ar2 = (const float*)d_in[14];
    const float* g2  = (const float*)d_in[15];
    const float* b2  = (const float*)d_in[16];
    const int* src   = (const int*)d_in[17];
    const int* dst   = (const int*)d_in[18];
    float* out = (float*)d_out;

    unsigned short* wt0 = (unsigned short*)d_ws;
    unsigned short* wt1 = wt0 + 256 * 64;
    unsigned short* wt2 = wt1 + 128 * 128;

    prep_w<<<64, 256, 0, stream>>>(W0, rW0, W1, W2, wt0, wt1, wt2);
    gat3_kernel<<<NGRAPH, 512, 0, stream>>>(
        x, wt0, wt1, wt2, al0, ar0, al1, ar1, al2, ar2,
        g0, b0, g1, b1, g2, b2, src, dst, out);
}